// Round 6
// baseline (36.693 us; speedup 1.0000x reference)
//
#include <hip/hip_runtime.h>
#include <cstdint>

namespace {

constexpr int NB = 320;   // batch
constexpr int ND = 128;   // feature dim
constexpr int NC = 80;    // label dim
constexpr int NANCH = 30;
constexpr int NW = 5;     // 64-bit words per 320-bit row

// ---- workspace layout (byte offsets) ----
constexpr size_t OFF_FD   = 0;          // float[320*320]
constexpr size_t OFF_PACK = 409600;     // u64[640]
constexpr size_t OFF_CNT  = 414720;     // float[320]
constexpr size_t OFF_DIV  = 416000;     // float[320]

// K1: per-row prep (src norm, label pack) + fd row + diversity mean.
// Bit-exact vs reference (absmax 0.0) -- UNCHANGED from R5 for clean A/B.
__global__ __launch_bounds__(256) void k_fd(
    const int* __restrict__ label,
    const float* __restrict__ src,
    const float* __restrict__ tgt,
    float* __restrict__ fd,
    unsigned long long* __restrict__ packed,
    float* __restrict__ cnt,
    float* __restrict__ divr)
{
    const int a = blockIdx.x;
    const int tid = threadIdx.x;
    const int w = tid >> 6, lane = tid & 63;

    __shared__ float sa[ND];
    __shared__ float snsa;
    __shared__ float red[256];

    if (tid < ND) sa[tid] = src[a * ND + tid];
    if (w == 0) {
        float s0 = src[a * ND + lane];
        float s1 = src[a * ND + lane + 64];
        float v = s0 * s0 + s1 * s1;
        for (int off = 32; off > 0; off >>= 1) v += __shfl_down(v, off);
        if (lane == 0) snsa = sqrtf(v);
    } else if (w == 1) {
        int l0 = label[a * NC + lane];
        int l1 = (lane < NC - 64) ? label[a * NC + 64 + lane] : 0;
        unsigned long long b0 = __ballot(l0 != 0);
        unsigned long long b1 = __ballot(l1 != 0);
        if (lane == 0) {
            packed[2 * a] = b0;
            packed[2 * a + 1] = b1;
            cnt[a] = (float)(__popcll(b0) + __popcll(b1));
        }
    }
    __syncthreads();

    const float nsa = snsa;
    float acc = 0.f;
    for (int j = tid; j < NB; j += 256) {
        const float4* tp = reinterpret_cast<const float4*>(tgt + j * ND);
        float dot = 0.f, tn = 0.f;
#pragma unroll
        for (int d = 0; d < ND / 4; ++d) {
            float4 t = tp[d];
            dot += sa[4 * d + 0] * t.x + sa[4 * d + 1] * t.y +
                   sa[4 * d + 2] * t.z + sa[4 * d + 3] * t.w;
            tn += t.x * t.x + t.y * t.y + t.z * t.z + t.w * t.w;
        }
        float sim = dot / fmaxf(nsa * sqrtf(tn), 1e-8f);
        float f = fmaxf(1.0f - sim, 0.0f);
        fd[a * NB + j] = f;
        acc += f;
    }
    red[tid] = acc;
    __syncthreads();
    for (int st = 128; st > 0; st >>= 1) {
        if (tid < st) red[tid] += red[tid + st];
        __syncthreads();
    }
    if (tid == 0) divr[a] = red[0] / (float)NB;
}

// K2: single 16-wave block, minimal-latency version.
//  - rank phase: scalar broadcast loads of divr (no LDS staging, no dv[])
//  - classification: direct coalesced global reads of packed/cnt; anchor-side
//    values hoisted to SGPRs via readfirstlane (r, wd are wave-uniform
//    because 320 = 5*64)
//  - fdr prefetch issued before classification so its latency overlaps
//  - 3 barriers total
__global__ __launch_bounds__(1024) void k_tail(
    const unsigned long long* __restrict__ packed,
    const float* __restrict__ cnt,
    const float* __restrict__ fd,
    const float* __restrict__ divr,
    float* __restrict__ out)
{
    const int tid = threadIdx.x;
    const int lane = tid & 63;
    const int wv = tid >> 6;                 // 0..15

    __shared__ int alist[NANCH];
    __shared__ float fdr[NANCH][NB];         // 38400 B
    __shared__ unsigned long long pmask[NANCH][NW], nmask[NANCH][NW];
    __shared__ int prod[NANCH];
    __shared__ double wsum[16];

    // ---- P0: top-30 via parallel rank (ties -> lowest index, = lax.top_k).
    // divr[j] has a wave-uniform address -> scalar loads, free broadcast.
    if (tid < NB) {
        const float ve = divr[tid];
        int rank = 0;
#pragma unroll 8
        for (int j = 0; j < NB; ++j) {
            float vj = divr[j];
            rank += (vj > ve) || (vj == ve && j < tid);
        }
        if (rank < NANCH) alist[rank] = tid;  // ranks unique -> no collision
    }
    __syncthreads();

    // ---- P1a: issue fdr prefetch (latency overlaps classification below)
    for (int u = tid; u < NANCH * (NB / 4); u += 1024) {
        int r = u / (NB / 4);
        int q = u - r * (NB / 4);
        reinterpret_cast<float4*>(fdr[r])[q] =
            reinterpret_cast<const float4*>(fd + (size_t)alist[r] * NB)[q];
    }

    // ---- P1b: classification, one ballot per (r, word); r, j>>6 wave-uniform
    for (int it = 0; it < 10; ++it) {
        const int u = tid + 1024 * it;
        if (u < NANCH * NB) {                      // wave-uniform guard
            const int r = u / NB;
            const int j = u - r * NB;              // consecutive j across wave
            const int a2 = __builtin_amdgcn_readfirstlane(alist[r]);
            const unsigned long long a0 = packed[2 * a2];      // scalar loads
            const unsigned long long a1 = packed[2 * a2 + 1];
            const float sna = sqrtf(cnt[a2]);
            const float denom = sna * sqrtf(cnt[j]);
            const float dotf = (float)(__popcll(a0 & packed[2 * j]) +
                                       __popcll(a1 & packed[2 * j + 1]));
            const float ld = 1.0f - fminf(1.0f, dotf / denom);
            const bool valid = (j != a2) && (denom > 0.f); // zero-label -> NaN in ref -> excluded
            unsigned long long pb = __ballot(valid && (ld <= 0.2f));
            unsigned long long nb = __ballot(valid && (ld >= 0.5f));
            if (lane == 0) {
                pmask[r][j >> 6] = pb;
                nmask[r][j >> 6] = nb;
            }
        }
    }
    __syncthreads();                               // masks + fdr ready

    // ---- P2: per-anchor pair counts (wave 0 writes, thread 0 reads at end)
    if (tid < NANCH) {
        int p = 0, n = 0;
#pragma unroll
        for (int wd = 0; wd < NW; ++wd) {
            p += __popcll(pmask[tid][wd]);
            n += __popcll(nmask[tid][wd]);
        }
        prod[tid] = p * n;                         // pos/neg disjoint -> p != n
    }

    // ---- P3: triplet sum: parallel over (anchor, n); ctz loop over pos ----
    double s = 0.0;
    for (int it = 0; it < 10; ++it) {
        const int u = tid + 1024 * it;
        if (u < NANCH * NB) {
            const int r = u / NB, j = u - r * NB;
            if ((nmask[r][j >> 6] >> (j & 63)) & 1ull) {
                const float fn = fdr[r][j];
#pragma unroll
                for (int wd = 0; wd < NW; ++wd) {
                    unsigned long long m = pmask[r][wd];
                    while (m) {
                        const int b = __builtin_ctzll(m);
                        m &= m - 1;
                        float v = fdr[r][wd * 64 + b] - fn + 0.5f;
                        if (v > 0.f) s += (double)v;
                    }
                }
            }
        }
    }
    for (int off = 32; off > 0; off >>= 1) s += __shfl_down(s, off);
    if (lane == 0) wsum[wv] = s;
    __syncthreads();
    if (wv == 0) {
        double t = (lane < 16) ? wsum[lane] : 0.0;
        for (int off = 8; off > 0; off >>= 1) t += __shfl_down(t, off);
        if (lane == 0) {
            int c = 0;
#pragma unroll
            for (int r = 0; r < NANCH; ++r) c += prod[r];
            out[0] = (float)(t / ((double)c + 1e-4));
        }
    }
}

} // namespace

extern "C" void kernel_launch(void* const* d_in, const int* in_sizes, int n_in,
                              void* d_out, int out_size, void* d_ws, size_t ws_size,
                              hipStream_t stream) {
    const int* label = (const int*)d_in[0];
    const float* src = (const float*)d_in[1];
    const float* tgt = (const float*)d_in[2];

    char* ws = (char*)d_ws;
    float* fd = (float*)(ws + OFF_FD);
    unsigned long long* packed = (unsigned long long*)(ws + OFF_PACK);
    float* cnt = (float*)(ws + OFF_CNT);
    float* divr = (float*)(ws + OFF_DIV);

    k_fd  <<<NB, 256, 0, stream>>>(label, src, tgt, fd, packed, cnt, divr);
    k_tail<<<1, 1024, 0, stream>>>(packed, cnt, fd, divr, (float*)d_out);
}